// Round 9
// baseline (864.704 us; speedup 1.0000x reference)
//
#include <hip/hip_runtime.h>
#include <math.h>

#define NN 100000
#define NR 8
#define NE 640000
#define SEGN (NN * NR)                 // 800000
#define SPB 2048                       // segments per scan block
#define NSB ((SEGN + SPB - 1) / SPB)   // 391

#define TILES 1563                     // ceil(NN/64)
#define HT1 782
#define HT2 781
#define HP1 (HT1 * 64)                 // 50048
#define HP2 (HT2 * 64)                 // 49984
#define HPF (TILES * 64)               // 100032

typedef __attribute__((ext_vector_type(8))) __bf16 bf16x8;
typedef __attribute__((ext_vector_type(4))) float  f32x4;

__device__ __forceinline__ float bf2f(unsigned short b) {
    return __uint_as_float((unsigned)b << 16);
}
__device__ __forceinline__ unsigned short f2bf(float v) {
    __bf16 b = (__bf16)v;
    return __builtin_bit_cast(unsigned short, b);
}

// ---------------- preprocessing: CSR by (rel, dst) ----------------
// seg = rel * NN + dst  -> edges of a node-range for fixed rel are CONTIGUOUS.

__global__ __launch_bounds__(256) void count_kernel(
    const int* __restrict__ dst, const int* __restrict__ et, unsigned* __restrict__ cnt) {
    int e = blockIdx.x * 256 + threadIdx.x;
    if (e < NE) atomicAdd(&cnt[(size_t)et[e] * NN + dst[e]], 1u);
}

__global__ __launch_bounds__(256) void scan1_kernel(
    const unsigned* __restrict__ cnt, unsigned* __restrict__ bsum) {
    __shared__ unsigned red[256];
    int b = blockIdx.x, t = threadIdx.x;
    int i0 = b * SPB;
    unsigned s = 0;
#pragma unroll
    for (int k = 0; k < SPB / 256; ++k) {
        int i = i0 + k * 256 + t;
        if (i < SEGN) s += cnt[i];
    }
    red[t] = s;
    __syncthreads();
    for (int off = 128; off >= 1; off >>= 1) {
        if (t < off) red[t] += red[t + off];
        __syncthreads();
    }
    if (t == 0) bsum[b] = red[0];
}

__global__ __launch_bounds__(512) void scan2_kernel(
    unsigned* __restrict__ bsum, int* __restrict__ segoff) {
    __shared__ unsigned buf[512];
    int t = threadIdx.x;
    unsigned v = (t < NSB) ? bsum[t] : 0u;
    buf[t] = v;
    __syncthreads();
    for (int off = 1; off < 512; off <<= 1) {
        unsigned w = (t >= off) ? buf[t - off] : 0u;
        __syncthreads();
        buf[t] += w;
        __syncthreads();
    }
    if (t < NSB) bsum[t] = buf[t] - v;   // exclusive block offsets
    if (t == 0) segoff[SEGN] = NE;
}

__global__ __launch_bounds__(256) void scan3_kernel(
    const unsigned* __restrict__ cnt, const unsigned* __restrict__ bsum,
    int* __restrict__ segoff) {
    __shared__ unsigned lc[SPB];
    __shared__ unsigned tsum[256];
    int b = blockIdx.x, t = threadIdx.x;
    int i0 = b * SPB;
#pragma unroll
    for (int k = 0; k < SPB / 256; ++k) {
        int i = i0 + k * 256 + t;
        lc[k * 256 + t] = (i < SEGN) ? cnt[i] : 0u;
    }
    __syncthreads();
    unsigned s = 0;
#pragma unroll
    for (int k = 0; k < 8; ++k) s += lc[t * 8 + k];
    tsum[t] = s;
    __syncthreads();
    for (int off = 1; off < 256; off <<= 1) {
        unsigned w = (t >= off) ? tsum[t - off] : 0u;
        __syncthreads();
        tsum[t] += w;
        __syncthreads();
    }
    unsigned base = bsum[b] + tsum[t] - s;
#pragma unroll
    for (int k = 0; k < 8; ++k) {
        unsigned c = lc[t * 8 + k];
        lc[t * 8 + k] = base;
        base += c;
    }
    __syncthreads();
#pragma unroll
    for (int k = 0; k < SPB / 256; ++k) {
        int i = i0 + k * 256 + t;
        if (i < SEGN) segoff[i] = (int)lc[k * 256 + t];
    }
}

// esrc word: bits [0,17) = src node, bits [17,19) = dst & 3 (bin within 4-aligned group)
__global__ __launch_bounds__(256) void fill_kernel(
    const int* __restrict__ src, const int* __restrict__ dst, const int* __restrict__ et,
    const int* __restrict__ segoff, unsigned* __restrict__ cursor, int* __restrict__ esrc) {
    int e = blockIdx.x * 256 + threadIdx.x;
    if (e >= NE) return;
    int d = dst[e];
    int seg = et[e] * NN + d;
    int pos = segoff[seg] + (int)atomicAdd(&cursor[seg], 1u);
    esrc[pos] = src[e] | ((d & 3) << 17);
}

// ---------------- weight pack: f32 -> bf16 in MFMA B-fragment order -------
// Row-position bijection sigma: for D=128 the agg rows are pair-swizzled
// (position 2d <-> dim d, 2d+1 <-> dim d+64); B uses the same k-bijection.

template <int D, int O>
__global__ __launch_bounds__(256) void pack_kernel(
    const float* __restrict__ W, const float* __restrict__ Wr, __bf16* __restrict__ Wp) {
    constexpr int KT = D / 32, NTN = O / 16;
    int idx = blockIdx.x * 256 + threadIdx.x;
    if (idx >= (NR + 1) * KT * NTN * 64) return;
    int l = idx & 63;
    int rest = idx >> 6;
    int nt = rest % NTN; rest /= NTN;
    int kt = rest % KT;
    int r  = rest / KT;
    const float* srcw = (r < NR) ? (W + (size_t)r * D * O) : Wr;
    int n  = nt * 16 + (l & 15);
    int k0 = kt * 32 + (l >> 4) * 8;
    bf16x8 v;
#pragma unroll
    for (int j = 0; j < 8; ++j) {
        int p  = k0 + j;
        int kd = (D == 128) ? ((p >> 1) + ((p & 1) << 6)) : p;
        v[j] = (__bf16)srcw[(size_t)kd * O + n];
    }
    *(bf16x8*)(Wp + (size_t)idx * 8) = v;
}

// ---------------- gather: dense agg tensor, wave per 4 segments ----------
// agg[(r*HP + i)*D + p] bf16 (p = swizzled position for D=128), r==8 root.
// NT stores: agg is write-once/read-once -> keep x resident in L3.
// XF: 0 = f32 rows[64]  1 = bf16 pair-swizzled u32[64] (D=128)
//     2 = bf16 plain ushort[64] (D=64)

template <int D, int XF>
__global__ __launch_bounds__(256) void gather_kernel(
    const void* __restrict__ xin, const int* __restrict__ segoff,
    const int* __restrict__ esrc, ushort* __restrict__ agg,
    int base, int HP)
{
    int wv = threadIdx.x >> 6, ln = threadIdx.x & 63;
    int r  = blockIdx.y;
    int i0 = blockIdx.x * 16 + wv * 4;   // this wave's 4 rows (4-aligned)
    int n0 = base + i0;

    const float*    xf = (const float*)xin;
    const ushort*   xb = (const ushort*)xin;
    const unsigned* xs = (const unsigned*)xin;

    if (r < 8) {
        float ax[4] = {0, 0, 0, 0}, ay[4] = {0, 0, 0, 0};
        int eo[5];
#pragma unroll
        for (int k = 0; k <= 4; ++k) {
            int node = n0 + k; if (node > NN) node = NN;
            eo[k] = segoff[r * NN + node];
        }
        for (int ei = eo[0]; ei < eo[4]; ei += 4) {
            int nb = eo[4] - ei; if (nb > 4) nb = 4;
            int mm[4]; float vx[4], vy[4];
#pragma unroll
            for (int b = 0; b < 4; ++b) mm[b] = (b < nb) ? esrc[ei + b] : 0;
#pragma unroll
            for (int b = 0; b < 4; ++b) {
                if (b < nb) {
                    int s = mm[b] & 0x1FFFF;
                    if constexpr (XF == 0) {
                        vx[b] = xf[(size_t)s * 64 + ln];
                    } else if constexpr (XF == 1) {
                        unsigned w = xs[(size_t)s * 64 + ln];
                        vx[b] = bf2f((unsigned short)(w & 0xFFFFu));
                        vy[b] = bf2f((unsigned short)(w >> 16));
                    } else {
                        vx[b] = bf2f(xb[(size_t)s * 64 + ln]);
                    }
                }
            }
#pragma unroll
            for (int b = 0; b < 4; ++b) {
                if (b < nb) {
                    int k = mm[b] >> 17;
#pragma unroll
                    for (int kk = 0; kk < 4; ++kk) {
                        ax[kk] += (kk == k) ? vx[b] : 0.0f;
                        if constexpr (D == 128) ay[kk] += (kk == k) ? vy[b] : 0.0f;
                    }
                }
            }
        }
#pragma unroll
        for (int k = 0; k < 4; ++k) {
            int c = eo[k + 1] - eo[k];
            float sc = (c > 0) ? 1.0f / (float)c : 0.0f;
            size_t row = ((size_t)r * HP + i0 + k) * D;
            if constexpr (D == 128) {
                unsigned st = (unsigned)f2bf(ax[k] * sc) | ((unsigned)f2bf(ay[k] * sc) << 16);
                __builtin_nontemporal_store(st, (unsigned*)(agg + row) + ln);
            } else {
                __builtin_nontemporal_store(f2bf(ax[k] * sc), agg + row + ln);
            }
        }
    } else {
        // r == 8: root copy (zeros for pad rows)
#pragma unroll
        for (int k = 0; k < 4; ++k) {
            int n = n0 + k;
            size_t row = ((size_t)8 * HP + i0 + k) * D;
            if constexpr (D == 128) {
                unsigned w = 0;
                if (n < NN) w = xs[(size_t)n * 64 + ln];      // XF==1 here
                __builtin_nontemporal_store(w, (unsigned*)(agg + row) + ln);
            } else {
                ushort w = 0;
                if (n < NN) {
                    if constexpr (XF == 0) w = f2bf(xf[(size_t)n * 64 + ln]);
                    else                   w = xb[(size_t)n * 64 + ln];
                }
                __builtin_nontemporal_store(w, agg + row + ln);
            }
        }
    }
}

// ---------------- dense GEMM over K = 9*D, no LDS, no barriers -------------
// A-frags NT-loaded straight from agg (16B/lane); B from packed Wp (cached).
// MODE 0: relu+LN; 1: relu+resid+LN (resid from xres); 2: relu; 3: plain
// OF: 0 = f32 rows[O] (NT)  1 = bf16 pair-swizzled (O=128)  2 = bf16 plain (O=64)

template <int D, int O, int MODE, int OF>
__global__ __launch_bounds__(256) void gemm_layer(
    const ushort* __restrict__ agg, const __bf16* __restrict__ Wp,
    const float* __restrict__ bias, const float* __restrict__ gamma,
    const float* __restrict__ beta, const unsigned* __restrict__ xres,
    void* __restrict__ outv, int base, int HP)
{
    constexpr int KT = D / 32, NTN = O / 16;
    int t = threadIdx.x, wv = t >> 6, ln = t & 63, lg = ln >> 4, lm = ln & 15;
    int i0 = blockIdx.x * 64;

    f32x4 acc[NTN];
#pragma unroll
    for (int nt = 0; nt < NTN; ++nt)
#pragma unroll
        for (int q = 0; q < 4; ++q) acc[nt][q] = 0.0f;

    const ushort* abase = agg + ((size_t)(i0 + wv * 16 + lm)) * D + lg * 8;

#pragma unroll 1
    for (int r = 0; r < 9; ++r) {
        const ushort* ar = abase + (size_t)r * HP * D;
        const __bf16* bp = Wp + (((size_t)(r * KT) * NTN) << 9) + (ln << 3);
#pragma unroll
        for (int kt = 0; kt < KT; ++kt) {
            bf16x8 A = __builtin_nontemporal_load((const bf16x8*)(ar + kt * 32));
            const __bf16* bpk = bp + (((size_t)(kt * NTN)) << 9);
#pragma unroll
            for (int nt = 0; nt < NTN; ++nt) {
                bf16x8 B = *(const bf16x8*)(bpk + ((size_t)nt << 9));
                acc[nt] = __builtin_amdgcn_mfma_f32_16x16x32_bf16(A, B, acc[nt], 0, 0, 0);
            }
        }
    }

    // ---- epilogue (C/D layout: col = nt*16+lm, row = wv*16+lg*4+q) ----
    float bb[NTN], gg[NTN], be[NTN];
#pragma unroll
    for (int nt = 0; nt < NTN; ++nt) {
        bb[nt] = bias[nt * 16 + lm];
        if constexpr (MODE <= 1) {
            gg[nt] = gamma[nt * 16 + lm];
            be[nt] = beta[nt * 16 + lm];
        } else {
            gg[nt] = 0.0f; be[nt] = 0.0f;
        }
    }
#pragma unroll
    for (int q = 0; q < 4; ++q) {
        int row = wv * 16 + lg * 4 + q;
        int n = base + i0 + row;
        int nc = (n < NN) ? n : 0;
        float v[NTN];
#pragma unroll
        for (int nt = 0; nt < NTN; ++nt) {
            v[nt] = acc[nt][q] + bb[nt];
            if constexpr (MODE <= 2) v[nt] = fmaxf(v[nt], 0.0f);
            if constexpr (MODE == 1) {
                unsigned w = xres[(size_t)nc * 64 + (nt & 3) * 16 + lm];
                v[nt] += bf2f((unsigned short)((nt < 4) ? (w & 0xFFFFu) : (w >> 16)));
            }
        }
        if constexpr (MODE <= 1) {
            float s1 = 0.0f, s2 = 0.0f;
#pragma unroll
            for (int nt = 0; nt < NTN; ++nt) { s1 += v[nt]; s2 += v[nt] * v[nt]; }
#pragma unroll
            for (int off = 1; off < 16; off <<= 1) {
                s1 += __shfl_xor(s1, off, 64);
                s2 += __shfl_xor(s2, off, 64);
            }
            float mu  = s1 * (1.0f / O);
            float var = s2 * (1.0f / O) - mu * mu;
            float rs  = rsqrtf(var + 1e-5f);
#pragma unroll
            for (int nt = 0; nt < NTN; ++nt) v[nt] = (v[nt] - mu) * rs * gg[nt] + be[nt];
        }
        if (n < NN) {
            if constexpr (OF == 0) {
#pragma unroll
                for (int nt = 0; nt < NTN; ++nt)
                    __builtin_nontemporal_store(
                        v[nt], (float*)outv + (size_t)n * O + nt * 16 + lm);
            } else if constexpr (OF == 1) {          // O=128 pair-swizzled bf16
#pragma unroll
                for (int nt = 0; nt < 4; ++nt)
                    ((unsigned*)outv)[(size_t)n * 64 + nt * 16 + lm] =
                        (unsigned)f2bf(v[nt]) | ((unsigned)f2bf(v[nt + 4]) << 16);
            } else {                                  // O=64 plain bf16
#pragma unroll
                for (int nt = 0; nt < NTN; ++nt)
                    ((ushort*)outv)[(size_t)n * 64 + nt * 16 + lm] = f2bf(v[nt]);
            }
        }
    }
}

// ---------------- host launch ----------------

extern "C" void kernel_launch(void* const* d_in, const int* in_sizes, int n_in,
                              void* d_out, int out_size, void* d_ws, size_t ws_size,
                              hipStream_t stream) {
    const float* emb = (const float*)d_in[0];
    const float* W1  = (const float*)d_in[1];
    const float* R1  = (const float*)d_in[2];
    const float* B1  = (const float*)d_in[3];
    const float* W2  = (const float*)d_in[4];
    const float* R2  = (const float*)d_in[5];
    const float* B2  = (const float*)d_in[6];
    const float* W3  = (const float*)d_in[7];
    const float* R3  = (const float*)d_in[8];
    const float* B3  = (const float*)d_in[9];
    const float* W4  = (const float*)d_in[10];
    const float* R4  = (const float*)d_in[11];
    const float* B4  = (const float*)d_in[12];
    const float* g1  = (const float*)d_in[13];
    const float* b1  = (const float*)d_in[14];
    const float* g2  = (const float*)d_in[15];
    const float* b2  = (const float*)d_in[16];
    const int*   ei  = (const int*)d_in[17];
    const int*   et  = (const int*)d_in[18];
    const int* srcp = ei;
    const int* dstp = ei + NE;

    char* ws = (char*)d_ws;
    // layout (bytes):
    // segoff i32[800001]       @ 0            -> 3,200,016 (padded)
    // esrc   i32[640000]       @ 3,200,016    -> 5,760,016
    // Wp1    bf16[73728]       @ 5,760,016    -> 5,907,472
    // Wp2    bf16[147456]      @ 5,907,472    -> 6,202,384
    // Wp3    bf16[73728]       @ 6,202,384    -> 6,349,840
    // Wp4    bf16[36864]       @ 6,349,840    -> 6,423,568
    // x1     bf16-swz[NN*128]  @ 6,423,568    -> 32,023,568
    // x2     bf16-swz[NN*128]  @ 32,023,568   -> 57,623,568
    // x3     bf16[NN*64]       @ 57,623,568   -> 70,423,568
    // agg    bf16[max 57.66M]  @ 70,423,568   -> 185,734,160
    // transients (dead before first gather; aliased over agg):
    // cnt    u32[800000]       @ 70,423,568
    // cursor u32[800000]       @ 73,623,568
    // bsum   u32[512]          @ 76,823,568
    if (ws_size < 185734160u) return;
    int*      segoff = (int*)(ws + 0);
    int*      esrc   = (int*)(ws + 3200016);
    __bf16*   Wp1    = (__bf16*)(ws + 5760016);
    __bf16*   Wp2    = (__bf16*)(ws + 5907472);
    __bf16*   Wp3    = (__bf16*)(ws + 6202384);
    __bf16*   Wp4    = (__bf16*)(ws + 6349840);
    void*     x1     = (void*)(ws + 6423568);
    void*     x2     = (void*)(ws + 32023568);
    void*     x3     = (void*)(ws + 57623568);
    ushort*   agg    = (ushort*)(ws + 70423568);
    unsigned* cnt    = (unsigned*)(ws + 70423568);
    unsigned* cursor = (unsigned*)(ws + 73623568);
    unsigned* bsum   = (unsigned*)(ws + 76823568);
    float*    outp   = (float*)d_out;

    hipMemsetAsync(cnt, 0, 3200000, stream);
    hipMemsetAsync(cursor, 0, 3200000, stream);

    count_kernel<<<(NE + 255) / 256, 256, 0, stream>>>(dstp, et, cnt);
    scan1_kernel<<<NSB, 256, 0, stream>>>(cnt, bsum);
    scan2_kernel<<<1, 512, 0, stream>>>(bsum, segoff);
    scan3_kernel<<<NSB, 256, 0, stream>>>(cnt, bsum, segoff);
    fill_kernel<<<(NE + 255) / 256, 256, 0, stream>>>(
        srcp, dstp, et, segoff, cursor, esrc);

    pack_kernel<64, 128><<<(9 * 2 * 8 * 64 + 255) / 256, 256, 0, stream>>>(W1, R1, Wp1);
    pack_kernel<128, 128><<<(9 * 4 * 8 * 64 + 255) / 256, 256, 0, stream>>>(W2, R2, Wp2);
    pack_kernel<128, 64><<<(9 * 4 * 4 * 64 + 255) / 256, 256, 0, stream>>>(W3, R3, Wp3);
    pack_kernel<64, 64><<<(9 * 2 * 4 * 64 + 255) / 256, 256, 0, stream>>>(W4, R4, Wp4);

    // ---- Layer 1: emb f32(D=64) -> x1 swz-bf16(O=128), relu+LN. Full pass. ----
    gather_kernel<64, 0><<<dim3(HPF / 16, 9), 256, 0, stream>>>(emb, segoff, esrc, agg, 0, HPF);
    gemm_layer<64, 128, 0, 1><<<TILES, 256, 0, stream>>>(
        agg, Wp1, B1, g1, b1, nullptr, x1, 0, HPF);

    // ---- Layer 2: x1(D=128) -> x2(O=128), relu+resid+LN. Two halves. ----
    gather_kernel<128, 1><<<dim3(HP1 / 16, 9), 256, 0, stream>>>(x1, segoff, esrc, agg, 0, HP1);
    gemm_layer<128, 128, 1, 1><<<HT1, 256, 0, stream>>>(
        agg, Wp2, B2, g2, b2, (const unsigned*)x1, x2, 0, HP1);
    gather_kernel<128, 1><<<dim3(HP2 / 16, 9), 256, 0, stream>>>(x1, segoff, esrc, agg, HP1, HP2);
    gemm_layer<128, 128, 1, 1><<<HT2, 256, 0, stream>>>(
        agg, Wp2, B2, g2, b2, (const unsigned*)x1, x2, HP1, HP2);

    // ---- Layer 3: x2(D=128) -> x3 bf16(O=64), relu. Two halves. ----
    gather_kernel<128, 1><<<dim3(HP1 / 16, 9), 256, 0, stream>>>(x2, segoff, esrc, agg, 0, HP1);
    gemm_layer<128, 64, 2, 2><<<HT1, 256, 0, stream>>>(
        agg, Wp3, B3, nullptr, nullptr, nullptr, x3, 0, HP1);
    gather_kernel<128, 1><<<dim3(HP2 / 16, 9), 256, 0, stream>>>(x2, segoff, esrc, agg, HP1, HP2);
    gemm_layer<128, 64, 2, 2><<<HT2, 256, 0, stream>>>(
        agg, Wp3, B3, nullptr, nullptr, nullptr, x3, HP1, HP2);

    // ---- Layer 4: x3 bf16(D=64) -> out f32(O=64), plain. Full pass. ----
    gather_kernel<64, 2><<<dim3(HPF / 16, 9), 256, 0, stream>>>(x3, segoff, esrc, agg, 0, HPF);
    gemm_layer<64, 64, 3, 0><<<TILES, 256, 0, stream>>>(
        agg, Wp4, B4, nullptr, nullptr, nullptr, outp, 0, HPF);
}

// Round 10
// 782.549 us; speedup vs baseline: 1.1050x; 1.1050x over previous
//
#include <hip/hip_runtime.h>
#include <math.h>

#define NN 100000
#define NR 8
#define NE 640000
#define SEGN (NN * NR)                 // 800000
#define SPB 2048                       // segments per scan block
#define NSB ((SEGN + SPB - 1) / SPB)   // 391

#define TILES 1563                     // ceil(NN/64)
#define HT1 782
#define HT2 781
#define HP1 (HT1 * 64)                 // 50048
#define HP2 (HT2 * 64)                 // 49984
#define HPF (TILES * 64)               // 100032

typedef __attribute__((ext_vector_type(8))) __bf16 bf16x8;
typedef __attribute__((ext_vector_type(4))) float  f32x4;

__device__ __forceinline__ float bf2f(unsigned short b) {
    return __uint_as_float((unsigned)b << 16);
}
__device__ __forceinline__ unsigned short f2bf(float v) {
    __bf16 b = (__bf16)v;
    return __builtin_bit_cast(unsigned short, b);
}

// ---------------- preprocessing: CSR by (rel, dst) ----------------

__global__ __launch_bounds__(256) void count_kernel(
    const int* __restrict__ dst, const int* __restrict__ et, unsigned* __restrict__ cnt) {
    int e = blockIdx.x * 256 + threadIdx.x;
    if (e < NE) atomicAdd(&cnt[(size_t)et[e] * NN + dst[e]], 1u);
}

__global__ __launch_bounds__(256) void scan1_kernel(
    const unsigned* __restrict__ cnt, unsigned* __restrict__ bsum) {
    __shared__ unsigned red[256];
    int b = blockIdx.x, t = threadIdx.x;
    int i0 = b * SPB;
    unsigned s = 0;
#pragma unroll
    for (int k = 0; k < SPB / 256; ++k) {
        int i = i0 + k * 256 + t;
        if (i < SEGN) s += cnt[i];
    }
    red[t] = s;
    __syncthreads();
    for (int off = 128; off >= 1; off >>= 1) {
        if (t < off) red[t] += red[t + off];
        __syncthreads();
    }
    if (t == 0) bsum[b] = red[0];
}

__global__ __launch_bounds__(512) void scan2_kernel(
    unsigned* __restrict__ bsum, int* __restrict__ segoff) {
    __shared__ unsigned buf[512];
    int t = threadIdx.x;
    unsigned v = (t < NSB) ? bsum[t] : 0u;
    buf[t] = v;
    __syncthreads();
    for (int off = 1; off < 512; off <<= 1) {
        unsigned w = (t >= off) ? buf[t - off] : 0u;
        __syncthreads();
        buf[t] += w;
        __syncthreads();
    }
    if (t < NSB) bsum[t] = buf[t] - v;
    if (t == 0) segoff[SEGN] = NE;
}

__global__ __launch_bounds__(256) void scan3_kernel(
    const unsigned* __restrict__ cnt, const unsigned* __restrict__ bsum,
    int* __restrict__ segoff) {
    __shared__ unsigned lc[SPB];
    __shared__ unsigned tsum[256];
    int b = blockIdx.x, t = threadIdx.x;
    int i0 = b * SPB;
#pragma unroll
    for (int k = 0; k < SPB / 256; ++k) {
        int i = i0 + k * 256 + t;
        lc[k * 256 + t] = (i < SEGN) ? cnt[i] : 0u;
    }
    __syncthreads();
    unsigned s = 0;
#pragma unroll
    for (int k = 0; k < 8; ++k) s += lc[t * 8 + k];
    tsum[t] = s;
    __syncthreads();
    for (int off = 1; off < 256; off <<= 1) {
        unsigned w = (t >= off) ? tsum[t - off] : 0u;
        __syncthreads();
        tsum[t] += w;
        __syncthreads();
    }
    unsigned base = bsum[b] + tsum[t] - s;
#pragma unroll
    for (int k = 0; k < 8; ++k) {
        unsigned c = lc[t * 8 + k];
        lc[t * 8 + k] = base;
        base += c;
    }
    __syncthreads();
#pragma unroll
    for (int k = 0; k < SPB / 256; ++k) {
        int i = i0 + k * 256 + t;
        if (i < SEGN) segoff[i] = (int)lc[k * 256 + t];
    }
}

// esrc word: bits [0,17) = src node, bits [17,19) = dst & 3
__global__ __launch_bounds__(256) void fill_kernel(
    const int* __restrict__ src, const int* __restrict__ dst, const int* __restrict__ et,
    const int* __restrict__ segoff, unsigned* __restrict__ cursor, int* __restrict__ esrc) {
    int e = blockIdx.x * 256 + threadIdx.x;
    if (e >= NE) return;
    int d = dst[e];
    int seg = et[e] * NN + d;
    int pos = segoff[seg] + (int)atomicAdd(&cursor[seg], 1u);
    esrc[pos] = src[e] | ((d & 3) << 17);
}

// ---------------- weight pack: f32 -> bf16 in MFMA B-fragment order -------
// For D=128 the agg/x rows are pair-swizzled (pos 2d <-> dim d, 2d+1 <-> dim d+64);
// B uses the same k-bijection so the MFMA k-sum pairs correctly.

template <int D, int O>
__global__ __launch_bounds__(256) void pack_kernel(
    const float* __restrict__ W, const float* __restrict__ Wr, __bf16* __restrict__ Wp) {
    constexpr int KT = D / 32, NTN = O / 16;
    int idx = blockIdx.x * 256 + threadIdx.x;
    if (idx >= (NR + 1) * KT * NTN * 64) return;
    int l = idx & 63;
    int rest = idx >> 6;
    int nt = rest % NTN; rest /= NTN;
    int kt = rest % KT;
    int r  = rest / KT;
    const float* srcw = (r < NR) ? (W + (size_t)r * D * O) : Wr;
    int n  = nt * 16 + (l & 15);
    int k0 = kt * 32 + (l >> 4) * 8;
    bf16x8 v;
#pragma unroll
    for (int j = 0; j < 8; ++j) {
        int p  = k0 + j;
        int kd = (D == 128) ? ((p >> 1) + ((p & 1) << 6)) : p;
        v[j] = (__bf16)srcw[(size_t)kd * O + n];
    }
    *(bf16x8*)(Wp + (size_t)idx * 8) = v;
}

// ---------------- gather: dense agg (8 rel planes), wave per 4 segments ----
// agg[(r*HP + agg_off + i)*D + p] bf16. Chunked so x stays L3-resident.
// XF: 0 = f32 rows[64]  1 = bf16 pair-swizzled u32[64] (D=128)
//     2 = bf16 plain ushort[64] (D=64)

template <int D, int XF>
__global__ __launch_bounds__(256) void gather_kernel(
    const void* __restrict__ xin, const int* __restrict__ segoff,
    const int* __restrict__ esrc, ushort* __restrict__ agg,
    int nbase, int agg_off, int HP)
{
    int wv = threadIdx.x >> 6, ln = threadIdx.x & 63;
    int r  = blockIdx.y;
    int i0 = blockIdx.x * 16 + wv * 4;
    int n0 = nbase + i0;

    const float*    xf = (const float*)xin;
    const ushort*   xb = (const ushort*)xin;
    const unsigned* xs = (const unsigned*)xin;

    float ax[4] = {0, 0, 0, 0}, ay[4] = {0, 0, 0, 0};
    int eo[5];
#pragma unroll
    for (int k = 0; k <= 4; ++k) {
        int node = n0 + k; if (node > NN) node = NN;
        eo[k] = segoff[r * NN + node];
    }
    for (int ei = eo[0]; ei < eo[4]; ei += 4) {
        int nb = eo[4] - ei; if (nb > 4) nb = 4;
        int mm[4]; float vx[4], vy[4];
#pragma unroll
        for (int b = 0; b < 4; ++b) mm[b] = (b < nb) ? esrc[ei + b] : 0;
#pragma unroll
        for (int b = 0; b < 4; ++b) {
            if (b < nb) {
                int s = mm[b] & 0x1FFFF;
                if constexpr (XF == 0) {
                    vx[b] = xf[(size_t)s * 64 + ln];
                } else if constexpr (XF == 1) {
                    unsigned w = xs[(size_t)s * 64 + ln];
                    vx[b] = bf2f((unsigned short)(w & 0xFFFFu));
                    vy[b] = bf2f((unsigned short)(w >> 16));
                } else {
                    vx[b] = bf2f(xb[(size_t)s * 64 + ln]);
                }
            }
        }
#pragma unroll
        for (int b = 0; b < 4; ++b) {
            if (b < nb) {
                int k = mm[b] >> 17;
#pragma unroll
                for (int kk = 0; kk < 4; ++kk) {
                    ax[kk] += (kk == k) ? vx[b] : 0.0f;
                    if constexpr (D == 128) ay[kk] += (kk == k) ? vy[b] : 0.0f;
                }
            }
        }
    }
#pragma unroll
    for (int k = 0; k < 4; ++k) {
        int c = eo[k + 1] - eo[k];
        float sc = (c > 0) ? 1.0f / (float)c : 0.0f;
        size_t row = ((size_t)r * HP + agg_off + i0 + k) * D;
        if constexpr (D == 128) {
            unsigned st = (unsigned)f2bf(ax[k] * sc) | ((unsigned)f2bf(ay[k] * sc) << 16);
            *((unsigned*)(agg + row) + ln) = st;
        } else {
            agg[row + ln] = f2bf(ax[k] * sc);
        }
    }
}

// ---------------- dense GEMM over K = 9*D, no LDS, no barriers -------------
// r<8: A from agg (L3-hot).  r==8 (root): A straight from layer input x.
// MODE 0: relu+LN; 1: relu+resid+LN; 2: relu; 3: plain
// XF as gather. OF: 0 = f32 rows[O] (NT) 1 = bf16 pair-swz (O=128) 2 = bf16 (O=64)

template <int D, int O, int MODE, int XF, int OF>
__global__ __launch_bounds__(256) void gemm_layer(
    const ushort* __restrict__ agg, const __bf16* __restrict__ Wp,
    const float* __restrict__ bias, const float* __restrict__ gamma,
    const float* __restrict__ beta, const unsigned* __restrict__ xres,
    const void* __restrict__ xroot, void* __restrict__ outv, int base, int HP)
{
    constexpr int KT = D / 32, NTN = O / 16;
    int t = threadIdx.x, wv = t >> 6, ln = t & 63, lg = ln >> 4, lm = ln & 15;
    int i0 = blockIdx.x * 64;

    f32x4 acc[NTN];
#pragma unroll
    for (int nt = 0; nt < NTN; ++nt)
#pragma unroll
        for (int q = 0; q < 4; ++q) acc[nt][q] = 0.0f;

    const ushort* abase = agg + ((size_t)(i0 + wv * 16 + lm)) * D + lg * 8;

#pragma unroll 1
    for (int r = 0; r < 8; ++r) {
        const ushort* ar = abase + (size_t)r * HP * D;
        const __bf16* bp = Wp + (((size_t)(r * KT) * NTN) << 9) + (ln << 3);
#pragma unroll
        for (int kt = 0; kt < KT; ++kt) {
            bf16x8 A = *(const bf16x8*)(ar + kt * 32);
            const __bf16* bpk = bp + (((size_t)(kt * NTN)) << 9);
#pragma unroll
            for (int nt = 0; nt < NTN; ++nt) {
                bf16x8 B = *(const bf16x8*)(bpk + ((size_t)nt << 9));
                acc[nt] = __builtin_amdgcn_mfma_f32_16x16x32_bf16(A, B, acc[nt], 0, 0, 0);
            }
        }
    }
    // r == 8: root term, A directly from layer input (clamped pad rows)
    {
        int nrow = base + i0 + wv * 16 + lm;
        if (nrow >= NN) nrow = NN - 1;
        const __bf16* bp = Wp + (((size_t)(8 * KT) * NTN) << 9) + (ln << 3);
#pragma unroll
        for (int kt = 0; kt < KT; ++kt) {
            bf16x8 A;
            if constexpr (XF == 0) {
                const float* xp = (const float*)xroot + (size_t)nrow * 64 + kt * 32 + lg * 8;
                f32x4 a0 = *(const f32x4*)xp;
                f32x4 a1 = *(const f32x4*)(xp + 4);
#pragma unroll
                for (int j = 0; j < 4; ++j) { A[j] = (__bf16)a0[j]; A[j + 4] = (__bf16)a1[j]; }
            } else if constexpr (XF == 1) {
                A = *(const bf16x8*)((const ushort*)xroot + (size_t)nrow * 128 + kt * 32 + lg * 8);
            } else {
                A = *(const bf16x8*)((const ushort*)xroot + (size_t)nrow * 64 + kt * 32 + lg * 8);
            }
            const __bf16* bpk = bp + (((size_t)(kt * NTN)) << 9);
#pragma unroll
            for (int nt = 0; nt < NTN; ++nt) {
                bf16x8 B = *(const bf16x8*)(bpk + ((size_t)nt << 9));
                acc[nt] = __builtin_amdgcn_mfma_f32_16x16x32_bf16(A, B, acc[nt], 0, 0, 0);
            }
        }
    }

    // ---- epilogue (C/D layout: col = nt*16+lm, row = wv*16+lg*4+q) ----
    float bb[NTN], gg[NTN], be[NTN];
#pragma unroll
    for (int nt = 0; nt < NTN; ++nt) {
        bb[nt] = bias[nt * 16 + lm];
        if constexpr (MODE <= 1) {
            gg[nt] = gamma[nt * 16 + lm];
            be[nt] = beta[nt * 16 + lm];
        } else {
            gg[nt] = 0.0f; be[nt] = 0.0f;
        }
    }
#pragma unroll
    for (int q = 0; q < 4; ++q) {
        int row = wv * 16 + lg * 4 + q;
        int n = base + i0 + row;
        int nc = (n < NN) ? n : 0;
        float v[NTN];
#pragma unroll
        for (int nt = 0; nt < NTN; ++nt) {
            v[nt] = acc[nt][q] + bb[nt];
            if constexpr (MODE <= 2) v[nt] = fmaxf(v[nt], 0.0f);
            if constexpr (MODE == 1) {
                unsigned w = xres[(size_t)nc * 64 + (nt & 3) * 16 + lm];
                v[nt] += bf2f((unsigned short)((nt < 4) ? (w & 0xFFFFu) : (w >> 16)));
            }
        }
        if constexpr (MODE <= 1) {
            float s1 = 0.0f, s2 = 0.0f;
#pragma unroll
            for (int nt = 0; nt < NTN; ++nt) { s1 += v[nt]; s2 += v[nt] * v[nt]; }
#pragma unroll
            for (int off = 1; off < 16; off <<= 1) {
                s1 += __shfl_xor(s1, off, 64);
                s2 += __shfl_xor(s2, off, 64);
            }
            float mu  = s1 * (1.0f / O);
            float var = s2 * (1.0f / O) - mu * mu;
            float rs  = rsqrtf(var + 1e-5f);
#pragma unroll
            for (int nt = 0; nt < NTN; ++nt) v[nt] = (v[nt] - mu) * rs * gg[nt] + be[nt];
        }
        if (n < NN) {
            if constexpr (OF == 0) {
#pragma unroll
                for (int nt = 0; nt < NTN; ++nt)
                    __builtin_nontemporal_store(
                        v[nt], (float*)outv + (size_t)n * O + nt * 16 + lm);
            } else if constexpr (OF == 1) {
#pragma unroll
                for (int nt = 0; nt < 4; ++nt)
                    ((unsigned*)outv)[(size_t)n * 64 + nt * 16 + lm] =
                        (unsigned)f2bf(v[nt]) | ((unsigned)f2bf(v[nt + 4]) << 16);
            } else {
#pragma unroll
                for (int nt = 0; nt < NTN; ++nt)
                    ((ushort*)outv)[(size_t)n * 64 + nt * 16 + lm] = f2bf(v[nt]);
            }
        }
    }
}

// ---------------- host launch ----------------

extern "C" void kernel_launch(void* const* d_in, const int* in_sizes, int n_in,
                              void* d_out, int out_size, void* d_ws, size_t ws_size,
                              hipStream_t stream) {
    const float* emb = (const float*)d_in[0];
    const float* W1  = (const float*)d_in[1];
    const float* R1  = (const float*)d_in[2];
    const float* B1  = (const float*)d_in[3];
    const float* W2  = (const float*)d_in[4];
    const float* R2  = (const float*)d_in[5];
    const float* B2  = (const float*)d_in[6];
    const float* W3  = (const float*)d_in[7];
    const float* R3  = (const float*)d_in[8];
    const float* B3  = (const float*)d_in[9];
    const float* W4  = (const float*)d_in[10];
    const float* R4  = (const float*)d_in[11];
    const float* B4  = (const float*)d_in[12];
    const float* g1  = (const float*)d_in[13];
    const float* b1  = (const float*)d_in[14];
    const float* g2  = (const float*)d_in[15];
    const float* b2  = (const float*)d_in[16];
    const int*   ei  = (const int*)d_in[17];
    const int*   et  = (const int*)d_in[18];
    const int* srcp = ei;
    const int* dstp = ei + NE;

    char* ws = (char*)d_ws;
    // layout identical to round 7/9 (agg region reused, now 8 planes max 102.5 MB)
    if (ws_size < 185734160u) return;
    int*      segoff = (int*)(ws + 0);
    int*      esrc   = (int*)(ws + 3200016);
    __bf16*   Wp1    = (__bf16*)(ws + 5760016);
    __bf16*   Wp2    = (__bf16*)(ws + 5907472);
    __bf16*   Wp3    = (__bf16*)(ws + 6202384);
    __bf16*   Wp4    = (__bf16*)(ws + 6349840);
    void*     x1     = (void*)(ws + 6423568);
    void*     x2     = (void*)(ws + 32023568);
    void*     x3     = (void*)(ws + 57623568);
    ushort*   agg    = (ushort*)(ws + 70423568);
    unsigned* cnt    = (unsigned*)(ws + 70423568);
    unsigned* cursor = (unsigned*)(ws + 73623568);
    unsigned* bsum   = (unsigned*)(ws + 76823568);
    float*    outp   = (float*)d_out;

    hipMemsetAsync(cnt, 0, 3200000, stream);
    hipMemsetAsync(cursor, 0, 3200000, stream);

    count_kernel<<<(NE + 255) / 256, 256, 0, stream>>>(dstp, et, cnt);
    scan1_kernel<<<NSB, 256, 0, stream>>>(cnt, bsum);
    scan2_kernel<<<1, 512, 0, stream>>>(bsum, segoff);
    scan3_kernel<<<NSB, 256, 0, stream>>>(cnt, bsum, segoff);
    fill_kernel<<<(NE + 255) / 256, 256, 0, stream>>>(
        srcp, dstp, et, segoff, cursor, esrc);

    pack_kernel<64, 128><<<(9 * 2 * 8 * 64 + 255) / 256, 256, 0, stream>>>(W1, R1, Wp1);
    pack_kernel<128, 128><<<(9 * 4 * 8 * 64 + 255) / 256, 256, 0, stream>>>(W2, R2, Wp2);
    pack_kernel<128, 64><<<(9 * 4 * 4 * 64 + 255) / 256, 256, 0, stream>>>(W3, R3, Wp3);
    pack_kernel<64, 64><<<(9 * 2 * 4 * 64 + 255) / 256, 256, 0, stream>>>(W4, R4, Wp4);

    // chunk geometry: D=128 halves (HP1/HP2) each split in 2 gather chunks;
    // D=64 full pass split in 2 gather chunks.
    // ---- Layer 1: emb f32(64) -> x1 swz-bf16(128), relu+LN ----
    gather_kernel<64, 0><<<dim3(HP1 / 16, 8), 256, 0, stream>>>(emb, segoff, esrc, agg, 0, 0, HPF);
    gather_kernel<64, 0><<<dim3(HP2 / 16, 8), 256, 0, stream>>>(emb, segoff, esrc, agg, HP1, HP1, HPF);
    gemm_layer<64, 128, 0, 0, 1><<<TILES, 256, 0, stream>>>(
        agg, Wp1, B1, g1, b1, nullptr, emb, x1, 0, HPF);

    // ---- Layer 2: x1(128) -> x2(128), relu+resid+LN ----
    gather_kernel<128, 1><<<dim3(25024 / 16, 8), 256, 0, stream>>>(x1, segoff, esrc, agg, 0, 0, HP1);
    gather_kernel<128, 1><<<dim3(25024 / 16, 8), 256, 0, stream>>>(x1, segoff, esrc, agg, 25024, 25024, HP1);
    gemm_layer<128, 128, 1, 1, 1><<<HT1, 256, 0, stream>>>(
        agg, Wp2, B2, g2, b2, (const unsigned*)x1, x1, x2, 0, HP1);
    gather_kernel<128, 1><<<dim3(25024 / 16, 8), 256, 0, stream>>>(x1, segoff, esrc, agg, HP1, 0, HP2);
    gather_kernel<128, 1><<<dim3(24960 / 16, 8), 256, 0, stream>>>(x1, segoff, esrc, agg, HP1 + 25024, 25024, HP2);
    gemm_layer<128, 128, 1, 1, 1><<<HT2, 256, 0, stream>>>(
        agg, Wp2, B2, g2, b2, (const unsigned*)x1, x1, x2, HP1, HP2);

    // ---- Layer 3: x2(128) -> x3 bf16(64), relu ----
    gather_kernel<128, 1><<<dim3(25024 / 16, 8), 256, 0, stream>>>(x2, segoff, esrc, agg, 0, 0, HP1);
    gather_kernel<128, 1><<<dim3(25024 / 16, 8), 256, 0, stream>>>(x2, segoff, esrc, agg, 25024, 25024, HP1);
    gemm_layer<128, 64, 2, 1, 2><<<HT1, 256, 0, stream>>>(
        agg, Wp3, B3, nullptr, nullptr, nullptr, x2, x3, 0, HP1);
    gather_kernel<128, 1><<<dim3(25024 / 16, 8), 256, 0, stream>>>(x2, segoff, esrc, agg, HP1, 0, HP2);
    gather_kernel<128, 1><<<dim3(24960 / 16, 8), 256, 0, stream>>>(x2, segoff, esrc, agg, HP1 + 25024, 25024, HP2);
    gemm_layer<128, 64, 2, 1, 2><<<HT2, 256, 0, stream>>>(
        agg, Wp3, B3, nullptr, nullptr, nullptr, x2, x3, HP1, HP2);

    // ---- Layer 4: x3 bf16(64) -> out f32(64), plain ----
    gather_kernel<64, 2><<<dim3(HP1 / 16, 8), 256, 0, stream>>>(x3, segoff, esrc, agg, 0, 0, HPF);
    gather_kernel<64, 2><<<dim3(HP2 / 16, 8), 256, 0, stream>>>(x3, segoff, esrc, agg, HP1, HP1, HPF);
    gemm_layer<64, 64, 3, 2, 0><<<TILES, 256, 0, stream>>>(
        agg, Wp4, B4, nullptr, nullptr, nullptr, x3, outp, 0, HPF);
}

// Round 11
// 701.469 us; speedup vs baseline: 1.2327x; 1.1156x over previous
//
#include <hip/hip_runtime.h>
#include <math.h>

#define NN 100000
#define NR 8
#define NE 640000
#define SEGN (NN * NR)                 // 800000
#define SPB 2048                       // segments per scan block
#define NSB ((SEGN + SPB - 1) / SPB)   // 391

#define TILES 1563                     // ceil(NN/64)
#define HT1 782
#define HT2 781
#define HP1 (HT1 * 64)                 // 50048
#define HP2 (HT2 * 64)                 // 49984
#define HPF (TILES * 64)               // 100032

typedef __attribute__((ext_vector_type(8))) __bf16 bf16x8;
typedef __attribute__((ext_vector_type(4))) float  f32x4;

__device__ __forceinline__ float bf2f(unsigned short b) {
    return __uint_as_float((unsigned)b << 16);
}
__device__ __forceinline__ unsigned short f2bf(float v) {
    __bf16 b = (__bf16)v;
    return __builtin_bit_cast(unsigned short, b);
}

// ---------------- preprocessing: CSR by (rel, dst) ----------------

__global__ __launch_bounds__(256) void count_kernel(
    const int* __restrict__ dst, const int* __restrict__ et, unsigned* __restrict__ cnt) {
    int e = blockIdx.x * 256 + threadIdx.x;
    if (e < NE) atomicAdd(&cnt[(size_t)et[e] * NN + dst[e]], 1u);
}

__global__ __launch_bounds__(256) void scan1_kernel(
    const unsigned* __restrict__ cnt, unsigned* __restrict__ bsum) {
    __shared__ unsigned red[256];
    int b = blockIdx.x, t = threadIdx.x;
    int i0 = b * SPB;
    unsigned s = 0;
#pragma unroll
    for (int k = 0; k < SPB / 256; ++k) {
        int i = i0 + k * 256 + t;
        if (i < SEGN) s += cnt[i];
    }
    red[t] = s;
    __syncthreads();
    for (int off = 128; off >= 1; off >>= 1) {
        if (t < off) red[t] += red[t + off];
        __syncthreads();
    }
    if (t == 0) bsum[b] = red[0];
}

__global__ __launch_bounds__(512) void scan2_kernel(
    unsigned* __restrict__ bsum, int* __restrict__ segoff) {
    __shared__ unsigned buf[512];
    int t = threadIdx.x;
    unsigned v = (t < NSB) ? bsum[t] : 0u;
    buf[t] = v;
    __syncthreads();
    for (int off = 1; off < 512; off <<= 1) {
        unsigned w = (t >= off) ? buf[t - off] : 0u;
        __syncthreads();
        buf[t] += w;
        __syncthreads();
    }
    if (t < NSB) bsum[t] = buf[t] - v;
    if (t == 0) segoff[SEGN] = NE;
}

__global__ __launch_bounds__(256) void scan3_kernel(
    const unsigned* __restrict__ cnt, const unsigned* __restrict__ bsum,
    int* __restrict__ segoff) {
    __shared__ unsigned lc[SPB];
    __shared__ unsigned tsum[256];
    int b = blockIdx.x, t = threadIdx.x;
    int i0 = b * SPB;
#pragma unroll
    for (int k = 0; k < SPB / 256; ++k) {
        int i = i0 + k * 256 + t;
        lc[k * 256 + t] = (i < SEGN) ? cnt[i] : 0u;
    }
    __syncthreads();
    unsigned s = 0;
#pragma unroll
    for (int k = 0; k < 8; ++k) s += lc[t * 8 + k];
    tsum[t] = s;
    __syncthreads();
    for (int off = 1; off < 256; off <<= 1) {
        unsigned w = (t >= off) ? tsum[t - off] : 0u;
        __syncthreads();
        tsum[t] += w;
        __syncthreads();
    }
    unsigned base = bsum[b] + tsum[t] - s;
#pragma unroll
    for (int k = 0; k < 8; ++k) {
        unsigned c = lc[t * 8 + k];
        lc[t * 8 + k] = base;
        base += c;
    }
    __syncthreads();
#pragma unroll
    for (int k = 0; k < SPB / 256; ++k) {
        int i = i0 + k * 256 + t;
        if (i < SEGN) segoff[i] = (int)lc[k * 256 + t];
    }
}

// esrc word: bits [0,17) = src node, bits [17,19) = dst & 3
__global__ __launch_bounds__(256) void fill_kernel(
    const int* __restrict__ src, const int* __restrict__ dst, const int* __restrict__ et,
    const int* __restrict__ segoff, unsigned* __restrict__ cursor, int* __restrict__ esrc) {
    int e = blockIdx.x * 256 + threadIdx.x;
    if (e >= NE) return;
    int d = dst[e];
    int seg = et[e] * NN + d;
    int pos = segoff[seg] + (int)atomicAdd(&cursor[seg], 1u);
    esrc[pos] = src[e] | ((d & 3) << 17);
}

// ---------------- weight pack: f32 -> bf16 in MFMA B-fragment order -------
// For D=128 the agg/x rows are pair-swizzled (pos 2d <-> dim d, 2d+1 <-> dim d+64);
// B uses the same k-bijection so the MFMA k-sum pairs correctly.

template <int D, int O>
__global__ __launch_bounds__(256) void pack_kernel(
    const float* __restrict__ W, const float* __restrict__ Wr, __bf16* __restrict__ Wp) {
    constexpr int KT = D / 32, NTN = O / 16;
    int idx = blockIdx.x * 256 + threadIdx.x;
    if (idx >= (NR + 1) * KT * NTN * 64) return;
    int l = idx & 63;
    int rest = idx >> 6;
    int nt = rest % NTN; rest /= NTN;
    int kt = rest % KT;
    int r  = rest / KT;
    const float* srcw = (r < NR) ? (W + (size_t)r * D * O) : Wr;
    int n  = nt * 16 + (l & 15);
    int k0 = kt * 32 + (l >> 4) * 8;
    bf16x8 v;
#pragma unroll
    for (int j = 0; j < 8; ++j) {
        int p  = k0 + j;
        int kd = (D == 128) ? ((p >> 1) + ((p & 1) << 6)) : p;
        v[j] = (__bf16)srcw[(size_t)kd * O + n];
    }
    *(bf16x8*)(Wp + (size_t)idx * 8) = v;
}

// ---------------- gather: dense agg (8 rel planes), wave per 4 segments ----
// agg[(r*HP + agg_off + i)*D + p] bf16. Chunked so x stays L3-resident.
// XF: 0 = f32 rows[64]  1 = bf16 pair-swizzled u32[64] (D=128)
//     2 = bf16 plain ushort[64] (D=64)

template <int D, int XF>
__global__ __launch_bounds__(256) void gather_kernel(
    const void* __restrict__ xin, const int* __restrict__ segoff,
    const int* __restrict__ esrc, ushort* __restrict__ agg,
    int nbase, int agg_off, int HP)
{
    int wv = threadIdx.x >> 6, ln = threadIdx.x & 63;
    int r  = blockIdx.y;
    int i0 = blockIdx.x * 16 + wv * 4;
    int n0 = nbase + i0;

    const float*    xf = (const float*)xin;
    const ushort*   xb = (const ushort*)xin;
    const unsigned* xs = (const unsigned*)xin;

    float ax[4] = {0, 0, 0, 0}, ay[4] = {0, 0, 0, 0};
    int eo[5];
#pragma unroll
    for (int k = 0; k <= 4; ++k) {
        int node = n0 + k; if (node > NN) node = NN;
        eo[k] = segoff[r * NN + node];
    }
    for (int ei = eo[0]; ei < eo[4]; ei += 4) {
        int nb = eo[4] - ei; if (nb > 4) nb = 4;
        int mm[4]; float vx[4], vy[4];
#pragma unroll
        for (int b = 0; b < 4; ++b) mm[b] = (b < nb) ? esrc[ei + b] : 0;
#pragma unroll
        for (int b = 0; b < 4; ++b) {
            if (b < nb) {
                int s = mm[b] & 0x1FFFF;
                if constexpr (XF == 0) {
                    vx[b] = xf[(size_t)s * 64 + ln];
                } else if constexpr (XF == 1) {
                    unsigned w = xs[(size_t)s * 64 + ln];
                    vx[b] = bf2f((unsigned short)(w & 0xFFFFu));
                    vy[b] = bf2f((unsigned short)(w >> 16));
                } else {
                    vx[b] = bf2f(xb[(size_t)s * 64 + ln]);
                }
            }
        }
#pragma unroll
        for (int b = 0; b < 4; ++b) {
            if (b < nb) {
                int k = mm[b] >> 17;
#pragma unroll
                for (int kk = 0; kk < 4; ++kk) {
                    ax[kk] += (kk == k) ? vx[b] : 0.0f;
                    if constexpr (D == 128) ay[kk] += (kk == k) ? vy[b] : 0.0f;
                }
            }
        }
    }
#pragma unroll
    for (int k = 0; k < 4; ++k) {
        int c = eo[k + 1] - eo[k];
        float sc = (c > 0) ? 1.0f / (float)c : 0.0f;
        size_t row = ((size_t)r * HP + agg_off + i0 + k) * D;
        if constexpr (D == 128) {
            unsigned st = (unsigned)f2bf(ax[k] * sc) | ((unsigned)f2bf(ay[k] * sc) << 16);
            *((unsigned*)(agg + row) + ln) = st;
        } else {
            agg[row + ln] = f2bf(ax[k] * sc);
        }
    }
}

// ---------------- dense GEMM, 1 wave / 16 rows, software-pipelined ---------
// r<8: A from agg (L3-hot), prefetched one plane ahead.  Root A preloaded.
// MODE 0: relu+LN; 1: relu+resid+LN; 2: relu; 3: plain
// XF as gather. OF: 0 = f32 rows[O] (NT) 1 = bf16 pair-swz (O=128) 2 = bf16 (O=64)

template <int D, int O, int MODE, int XF, int OF>
__global__ __launch_bounds__(64) void gemm_layer(
    const ushort* __restrict__ agg, const __bf16* __restrict__ Wp,
    const float* __restrict__ bias, const float* __restrict__ gamma,
    const float* __restrict__ beta, const unsigned* __restrict__ xres,
    const void* __restrict__ xroot, void* __restrict__ outv, int base, int HP)
{
    constexpr int KT = D / 32, NTN = O / 16;
    int ln = threadIdx.x, lg = ln >> 4, lm = ln & 15;
    int i0 = blockIdx.x * 16;

    f32x4 acc[NTN];
#pragma unroll
    for (int nt = 0; nt < NTN; ++nt)
#pragma unroll
        for (int q = 0; q < 4; ++q) acc[nt][q] = 0.0f;

    // root A fragments: loaded first, live in registers for the whole kernel
    bf16x8 Aroot[KT];
    {
        int nrow = base + i0 + lm;
        if (nrow >= NN) nrow = NN - 1;
#pragma unroll
        for (int kt = 0; kt < KT; ++kt) {
            if constexpr (XF == 0) {
                const float* xp = (const float*)xroot + (size_t)nrow * 64 + kt * 32 + lg * 8;
                f32x4 a0 = *(const f32x4*)xp;
                f32x4 a1 = *(const f32x4*)(xp + 4);
#pragma unroll
                for (int j = 0; j < 4; ++j) {
                    Aroot[kt][j] = (__bf16)a0[j];
                    Aroot[kt][j + 4] = (__bf16)a1[j];
                }
            } else if constexpr (XF == 1) {
                Aroot[kt] = *(const bf16x8*)((const ushort*)xroot +
                                             (size_t)nrow * 128 + kt * 32 + lg * 8);
            } else {
                Aroot[kt] = *(const bf16x8*)((const ushort*)xroot +
                                             (size_t)nrow * 64 + kt * 32 + lg * 8);
            }
        }
    }

    const ushort* abase = agg + ((size_t)(i0 + lm)) * D + lg * 8;
    bf16x8 Acur[KT], Anxt[KT];
#pragma unroll
    for (int kt = 0; kt < KT; ++kt)
        Acur[kt] = *(const bf16x8*)(abase + kt * 32);

#pragma unroll 1
    for (int r = 0; r < 8; ++r) {
        // prefetch next plane's A while computing this one
        if (r < 7) {
            const ushort* an = abase + (size_t)(r + 1) * HP * D;
#pragma unroll
            for (int kt = 0; kt < KT; ++kt)
                Anxt[kt] = *(const bf16x8*)(an + kt * 32);
        }
        const __bf16* bp = Wp + (((size_t)(r * KT) * NTN) << 9) + (ln << 3);
#pragma unroll
        for (int kt = 0; kt < KT; ++kt) {
            const __bf16* bpk = bp + (((size_t)(kt * NTN)) << 9);
#pragma unroll
            for (int nt = 0; nt < NTN; ++nt) {
                bf16x8 B = *(const bf16x8*)(bpk + ((size_t)nt << 9));
                acc[nt] = __builtin_amdgcn_mfma_f32_16x16x32_bf16(Acur[kt], B, acc[nt], 0, 0, 0);
            }
        }
#pragma unroll
        for (int kt = 0; kt < KT; ++kt) Acur[kt] = Anxt[kt];
    }
    // root plane (index 8)
    {
        const __bf16* bp = Wp + (((size_t)(8 * KT) * NTN) << 9) + (ln << 3);
#pragma unroll
        for (int kt = 0; kt < KT; ++kt) {
            const __bf16* bpk = bp + (((size_t)(kt * NTN)) << 9);
#pragma unroll
            for (int nt = 0; nt < NTN; ++nt) {
                bf16x8 B = *(const bf16x8*)(bpk + ((size_t)nt << 9));
                acc[nt] = __builtin_amdgcn_mfma_f32_16x16x32_bf16(Aroot[kt], B, acc[nt], 0, 0, 0);
            }
        }
    }

    // ---- epilogue (C/D layout: col = nt*16+lm, row = lg*4+q) ----
    float bb[NTN], gg[NTN], be[NTN];
#pragma unroll
    for (int nt = 0; nt < NTN; ++nt) {
        bb[nt] = bias[nt * 16 + lm];
        if constexpr (MODE <= 1) {
            gg[nt] = gamma[nt * 16 + lm];
            be[nt] = beta[nt * 16 + lm];
        } else {
            gg[nt] = 0.0f; be[nt] = 0.0f;
        }
    }
#pragma unroll
    for (int q = 0; q < 4; ++q) {
        int row = lg * 4 + q;
        int n = base + i0 + row;
        int nc = (n < NN) ? n : 0;
        float v[NTN];
#pragma unroll
        for (int nt = 0; nt < NTN; ++nt) {
            v[nt] = acc[nt][q] + bb[nt];
            if constexpr (MODE <= 2) v[nt] = fmaxf(v[nt], 0.0f);
            if constexpr (MODE == 1) {
                unsigned w = xres[(size_t)nc * 64 + (nt & 3) * 16 + lm];
                v[nt] += bf2f((unsigned short)((nt < 4) ? (w & 0xFFFFu) : (w >> 16)));
            }
        }
        if constexpr (MODE <= 1) {
            float s1 = 0.0f, s2 = 0.0f;
#pragma unroll
            for (int nt = 0; nt < NTN; ++nt) { s1 += v[nt]; s2 += v[nt] * v[nt]; }
#pragma unroll
            for (int off = 1; off < 16; off <<= 1) {
                s1 += __shfl_xor(s1, off, 64);
                s2 += __shfl_xor(s2, off, 64);
            }
            float mu  = s1 * (1.0f / O);
            float var = s2 * (1.0f / O) - mu * mu;
            float rs  = rsqrtf(var + 1e-5f);
#pragma unroll
            for (int nt = 0; nt < NTN; ++nt) v[nt] = (v[nt] - mu) * rs * gg[nt] + be[nt];
        }
        if (n < NN) {
            if constexpr (OF == 0) {
#pragma unroll
                for (int nt = 0; nt < NTN; ++nt)
                    __builtin_nontemporal_store(
                        v[nt], (float*)outv + (size_t)n * O + nt * 16 + lm);
            } else if constexpr (OF == 1) {
#pragma unroll
                for (int nt = 0; nt < 4; ++nt)
                    ((unsigned*)outv)[(size_t)n * 64 + nt * 16 + lm] =
                        (unsigned)f2bf(v[nt]) | ((unsigned)f2bf(v[nt + 4]) << 16);
            } else {
#pragma unroll
                for (int nt = 0; nt < NTN; ++nt)
                    ((ushort*)outv)[(size_t)n * 64 + nt * 16 + lm] = f2bf(v[nt]);
            }
        }
    }
}

// ---------------- host launch ----------------

extern "C" void kernel_launch(void* const* d_in, const int* in_sizes, int n_in,
                              void* d_out, int out_size, void* d_ws, size_t ws_size,
                              hipStream_t stream) {
    const float* emb = (const float*)d_in[0];
    const float* W1  = (const float*)d_in[1];
    const float* R1  = (const float*)d_in[2];
    const float* B1  = (const float*)d_in[3];
    const float* W2  = (const float*)d_in[4];
    const float* R2  = (const float*)d_in[5];
    const float* B2  = (const float*)d_in[6];
    const float* W3  = (const float*)d_in[7];
    const float* R3  = (const float*)d_in[8];
    const float* B3  = (const float*)d_in[9];
    const float* W4  = (const float*)d_in[10];
    const float* R4  = (const float*)d_in[11];
    const float* B4  = (const float*)d_in[12];
    const float* g1  = (const float*)d_in[13];
    const float* b1  = (const float*)d_in[14];
    const float* g2  = (const float*)d_in[15];
    const float* b2  = (const float*)d_in[16];
    const int*   ei  = (const int*)d_in[17];
    const int*   et  = (const int*)d_in[18];
    const int* srcp = ei;
    const int* dstp = ei + NE;

    char* ws = (char*)d_ws;
    if (ws_size < 185734160u) return;
    int*      segoff = (int*)(ws + 0);
    int*      esrc   = (int*)(ws + 3200016);
    __bf16*   Wp1    = (__bf16*)(ws + 5760016);
    __bf16*   Wp2    = (__bf16*)(ws + 5907472);
    __bf16*   Wp3    = (__bf16*)(ws + 6202384);
    __bf16*   Wp4    = (__bf16*)(ws + 6349840);
    void*     x1     = (void*)(ws + 6423568);
    void*     x2     = (void*)(ws + 32023568);
    void*     x3     = (void*)(ws + 57623568);
    ushort*   agg    = (ushort*)(ws + 70423568);
    unsigned* cnt    = (unsigned*)(ws + 70423568);
    unsigned* cursor = (unsigned*)(ws + 73623568);
    unsigned* bsum   = (unsigned*)(ws + 76823568);
    float*    outp   = (float*)d_out;

    hipMemsetAsync(cnt, 0, 3200000, stream);
    hipMemsetAsync(cursor, 0, 3200000, stream);

    count_kernel<<<(NE + 255) / 256, 256, 0, stream>>>(dstp, et, cnt);
    scan1_kernel<<<NSB, 256, 0, stream>>>(cnt, bsum);
    scan2_kernel<<<1, 512, 0, stream>>>(bsum, segoff);
    scan3_kernel<<<NSB, 256, 0, stream>>>(cnt, bsum, segoff);
    fill_kernel<<<(NE + 255) / 256, 256, 0, stream>>>(
        srcp, dstp, et, segoff, cursor, esrc);

    pack_kernel<64, 128><<<(9 * 2 * 8 * 64 + 255) / 256, 256, 0, stream>>>(W1, R1, Wp1);
    pack_kernel<128, 128><<<(9 * 4 * 8 * 64 + 255) / 256, 256, 0, stream>>>(W2, R2, Wp2);
    pack_kernel<128, 64><<<(9 * 4 * 4 * 64 + 255) / 256, 256, 0, stream>>>(W3, R3, Wp3);
    pack_kernel<64, 64><<<(9 * 2 * 4 * 64 + 255) / 256, 256, 0, stream>>>(W4, R4, Wp4);

    // ---- Layer 1: emb f32(64) -> x1 swz-bf16(128), relu+LN ----
    gather_kernel<64, 0><<<dim3(HP1 / 16, 8), 256, 0, stream>>>(emb, segoff, esrc, agg, 0, 0, HPF);
    gather_kernel<64, 0><<<dim3(HP2 / 16, 8), 256, 0, stream>>>(emb, segoff, esrc, agg, HP1, HP1, HPF);
    gemm_layer<64, 128, 0, 0, 1><<<HPF / 16, 64, 0, stream>>>(
        agg, Wp1, B1, g1, b1, nullptr, emb, x1, 0, HPF);

    // ---- Layer 2: x1(128) -> x2(128), relu+resid+LN ----
    gather_kernel<128, 1><<<dim3(25024 / 16, 8), 256, 0, stream>>>(x1, segoff, esrc, agg, 0, 0, HP1);
    gather_kernel<128, 1><<<dim3(25024 / 16, 8), 256, 0, stream>>>(x1, segoff, esrc, agg, 25024, 25024, HP1);
    gemm_layer<128, 128, 1, 1, 1><<<HP1 / 16, 64, 0, stream>>>(
        agg, Wp2, B2, g2, b2, (const unsigned*)x1, x1, x2, 0, HP1);
    gather_kernel<128, 1><<<dim3(25024 / 16, 8), 256, 0, stream>>>(x1, segoff, esrc, agg, HP1, 0, HP2);
    gather_kernel<128, 1><<<dim3(24960 / 16, 8), 256, 0, stream>>>(x1, segoff, esrc, agg, HP1 + 25024, 25024, HP2);
    gemm_layer<128, 128, 1, 1, 1><<<HP2 / 16, 64, 0, stream>>>(
        agg, Wp2, B2, g2, b2, (const unsigned*)x1, x1, x2, HP1, HP2);

    // ---- Layer 3: x2(128) -> x3 bf16(64), relu ----
    gather_kernel<128, 1><<<dim3(25024 / 16, 8), 256, 0, stream>>>(x2, segoff, esrc, agg, 0, 0, HP1);
    gather_kernel<128, 1><<<dim3(25024 / 16, 8), 256, 0, stream>>>(x2, segoff, esrc, agg, 25024, 25024, HP1);
    gemm_layer<128, 64, 2, 1, 2><<<HP1 / 16, 64, 0, stream>>>(
        agg, Wp3, B3, nullptr, nullptr, nullptr, x2, x3, 0, HP1);
    gather_kernel<128, 1><<<dim3(25024 / 16, 8), 256, 0, stream>>>(x2, segoff, esrc, agg, HP1, 0, HP2);
    gather_kernel<128, 1><<<dim3(24960 / 16, 8), 256, 0, stream>>>(x2, segoff, esrc, agg, HP1 + 25024, 25024, HP2);
    gemm_layer<128, 64, 2, 1, 2><<<HP2 / 16, 64, 0, stream>>>(
        agg, Wp3, B3, nullptr, nullptr, nullptr, x2, x3, HP1, HP2);

    // ---- Layer 4: x3 bf16(64) -> out f32(64), plain ----
    gather_kernel<64, 2><<<dim3(HP1 / 16, 8), 256, 0, stream>>>(x3, segoff, esrc, agg, 0, 0, HPF);
    gather_kernel<64, 2><<<dim3(HP2 / 16, 8), 256, 0, stream>>>(x3, segoff, esrc, agg, HP1, HP1, HPF);
    gemm_layer<64, 64, 3, 2, 0><<<HPF / 16, 64, 0, stream>>>(
        agg, Wp4, B4, nullptr, nullptr, nullptr, x3, outp, 0, HPF);
}